// Round 4
// baseline (3067.348 us; speedup 1.0000x reference)
//
#include <hip/hip_runtime.h>
#include <hip/hip_cooperative_groups.h>
#include <math.h>

namespace cg = cooperative_groups;

#define BATCH 2
#define TSTEPS 8
#define NBLK 768

typedef __attribute__((ext_vector_type(8))) short s16x8;   // 8 bf16
typedef __attribute__((ext_vector_type(4))) float f32x4;   // MFMA accum

__device__ __forceinline__ float hsig(float v){ return fminf(fmaxf(0.2f*v+0.5f,0.f),1.f); }
__device__ __forceinline__ ushort f2bf(float f){
    uint u = __builtin_bit_cast(uint, f);
    u = (u + 0x7FFFu + ((u >> 16) & 1u)) >> 16;
    return (ushort)u;
}
__device__ __forceinline__ uint pack2bf(float lo, float hi){
    return (uint)f2bf(lo) | ((uint)f2bf(hi) << 16);
}

// pack W[k][g*Co+co] fp32 -> fragment-linear bf16
template<int KCH, int Co>
__device__ __forceinline__ void packw(const float* __restrict__ W, ushort* __restrict__ dst, int d){
    int j = d & 7, lane = (d >> 3) & 63;
    int q = lane >> 4, l = lane & 15;
    int rest = d >> 9;
    int c = rest % KCH, t_n = rest / KCH;
    int k = c*32 + q*8 + j;
    int np = t_n*16 + l;
    int g = np & 3, co = np >> 2;
    dst[d] = f2bf(W[(size_t)k*(4*Co) + g*Co + co]);
}

#define SZ_X    786432
#define SZ_WX1  884736
#define SZ_WH1  589824
#define SZ_WX2  294912
#define SZ_WH2  147456
#define SZ_WX3  73728
#define SZ_WH3  36864
#define SZ_PREP (SZ_X+SZ_WX1+SZ_WH1+SZ_WX2+SZ_WH2+SZ_WX3+SZ_WH3)

struct Params {
    const float *x, *Wx1, *Wh1, *b1, *g1, *be1, *mm1, *mv1;
    const float *Wx2, *Wh2, *b2, *g2, *be2, *mm2, *mv2;
    const float *Wx3, *Wh3, *b3, *g3, *be3, *mm3, *mv3;
    float *Zx1, *Zx2, *Zx3, *c1, *c2, *c3;
    char  *zbase;
    ushort *xpad, *x2pad, *x3pad, *h1A, *h1B, *h2A, *h2B, *h3A, *h3B;
    ushort *Wxp1, *Wxp2, *Wxp3, *Whp1, *Whp2, *Whp3;
    float *out;
};

__device__ __forceinline__ void prep_elem(int i, const Params& p){
    if (i < SZ_X){
        int c = i % 192; int r = i / 192;
        int xx = r % 16; r /= 16; int yy = r % 16; int bt = r / 16;
        p.xpad[((size_t)bt*18*18 + (yy+1)*18 + (xx+1))*192 + c] = f2bf(p.x[i]);
        return;
    } i -= SZ_X;
    if (i < SZ_WX1){ packw<54,128>(p.Wx1, p.Wxp1, i); return; } i -= SZ_WX1;
    if (i < SZ_WH1){ packw<36,128>(p.Wh1, p.Whp1, i); return; } i -= SZ_WH1;
    if (i < SZ_WX2){ packw<36, 64>(p.Wx2, p.Wxp2, i); return; } i -= SZ_WX2;
    if (i < SZ_WH2){ packw<18, 64>(p.Wh2, p.Whp2, i); return; } i -= SZ_WH2;
    if (i < SZ_WX3){ packw<18, 32>(p.Wx3, p.Wxp3, i); return; } i -= SZ_WX3;
    if (i < SZ_WH3){ packw< 9, 32>(p.Wh3, p.Whp3, i); }
}

// ---------------------------------------------------------------------------
// Conv-x role for ONE time slice t. Zsc overlays patch.
// ---------------------------------------------------------------------------
template<int CI, int CO, int H, int W>
__device__ __forceinline__ void conv_slice_role(char* smem, int lbid, int t,
    const ushort* __restrict__ Apad, const ushort* __restrict__ Wpk,
    const float* __restrict__ bias, float* __restrict__ Zx)
{
    constexpr int W_T = (W < 32) ? W : 32;
    constexpr int PR = (32/W_T) + 2, PPX = W_T + 2;
    constexpr int PCI = CI + 8;
    constexpr int KCH = 9*CI/32, CPT = CI/32;
    constexpr int HW = H*W, HP = H+2, WP = W+2;
    constexpr int N4 = 4*CO;
    constexpr int CH8 = CI/8;
    constexpr int TOT = PR*PPX*CH8;
    constexpr int TPB = HW/32;
    constexpr int PXT = 2*TPB;

    ushort* patch = (ushort*)smem;
    float*  Zsc   = (float*)smem;   // overlay, [32][132]

    const int tid = threadIdx.x, lane = tid & 63, wave = tid >> 6;
    const int quad = lane >> 4, l16 = lane & 15;
    const int lx = lbid % PXT, ly = lbid / PXT;
    const int b = lx / TPB;
    const int idx0 = (lx - b*TPB)*32;
    const int bt = b*TSTEPS + t;
    const int m0 = bt*HW + idx0;
    const int y0 = idx0 / W, x0 = idx0 - (idx0/W)*W;

    const ushort* gsrc = Apad + (size_t)bt*HP*WP*CI;
    for (int c = tid; c < TOT; c += 256){
        int pix = c / CH8, ch = c - pix*CH8;
        int prow = pix / PPX, ppx = pix - prow*PPX;
        *(uint4*)&patch[pix*PCI + ch*8] =
            *(const uint4*)(gsrc + ((size_t)(y0+prow)*WP + (x0+ppx))*CI + ch*8);
    }
    __syncthreads();

    const int tn0 = ly*8 + wave*2;
    const ushort* bptr0 = Wpk + ((size_t)tn0*KCH*64 + lane)*8;
    const ushort* bptr1 = Wpk + ((size_t)(tn0+1)*KCH*64 + lane)*8;

    int labase[2];
    #pragma unroll
    for (int s = 0; s < 2; ++s){
        int pp = s*16 + l16;
        int rp = pp / W_T, xp = pp - rp*W_T;
        labase[s] = (rp*PPX + xp)*PCI + quad*8;
    }

    f32x4 acc[2][2] = {};
    #pragma unroll
    for (int it = 0; it < KCH; ++it){
        const int tap = it / CPT, ci0 = (it - tap*CPT)*32;
        const int kh = tap/3, kw = tap - (tap/3)*3;
        const int off = (kh*PPX + kw)*PCI + ci0;
        s16x8 b0 = *(const s16x8*)(bptr0 + (size_t)it*512);
        s16x8 b1 = *(const s16x8*)(bptr1 + (size_t)it*512);
        s16x8 a0 = *(const s16x8*)&patch[labase[0] + off];
        s16x8 a1 = *(const s16x8*)&patch[labase[1] + off];
        acc[0][0] = __builtin_amdgcn_mfma_f32_16x16x32_bf16(a0, b0, acc[0][0], 0,0,0);
        acc[0][1] = __builtin_amdgcn_mfma_f32_16x16x32_bf16(a0, b1, acc[0][1], 0,0,0);
        acc[1][0] = __builtin_amdgcn_mfma_f32_16x16x32_bf16(a1, b0, acc[1][0], 0,0,0);
        acc[1][1] = __builtin_amdgcn_mfma_f32_16x16x32_bf16(a1, b1, acc[1][1], 0,0,0);
    }
    __syncthreads();   // patch dead; Zsc overlays it

    #pragma unroll
    for (int s = 0; s < 2; ++s){
        #pragma unroll
        for (int nt = 0; nt < 2; ++nt){
            const int col = ly*128 + wave*32 + nt*16 + l16;
            const float bv = bias[(col & 3)*CO + (col >> 2)];
            #pragma unroll
            for (int r = 0; r < 4; ++r)
                Zsc[(s*16 + quad*4 + r)*132 + wave*32 + nt*16 + l16] = acc[s][nt][r] + bv;
        }
    }
    __syncthreads();

    #pragma unroll
    for (int i = 0; i < 4; ++i){
        int c = i*256 + tid;
        int row = c >> 5, cc = (c & 31) << 2;
        *(float4*)&Zx[(size_t)(m0+row)*N4 + ly*128 + cc] = *(float4*)&Zsc[row*132 + cc];
    }
}

// ---------------------------------------------------------------------------
// LSTM step role (split-K over 4 waves, LDS reduce, fused gates+BN+upsample).
// ---------------------------------------------------------------------------
template<int CO, int H, int W, int OUT_BF16>
__device__ __forceinline__ void step_role(char* smem, int lbid, int t, int first,
    const float* __restrict__ Zx, const ushort* __restrict__ Whpk,
    const ushort* __restrict__ hprev, ushort* __restrict__ hnew,
    float* __restrict__ cst,
    const float* __restrict__ gamma, const float* __restrict__ beta,
    const float* __restrict__ mmean, const float* __restrict__ mvar,
    void* __restrict__ outp)
{
    constexpr int W_T = (W < 32) ? W : 32;
    constexpr int PR = (32/W_T) + 2, PPX = W_T + 2;
    constexpr int PCO = CO + 8;
    constexpr int KCH = 9*CO/32, CPT = CO/32;
    constexpr int NJ = (KCH + 3)/4;
    constexpr int HW = H*W, HP = H+2, WP = W+2;
    constexpr int N4 = 4*CO;
    constexpr int CH8 = CO/8;
    constexpr int TOT = PR*PPX*CH8;
    constexpr int PT = (BATCH*HW)/32;

    ushort* patch = (ushort*)smem;
    float* Zs = (float*)smem;                   // overlay, [4][32][36]
    float* Hs = (float*)(smem + 18432);         // [32][8]

    const int tid = threadIdx.x, lane = tid & 63, wave = tid >> 6;
    const int quad = lane >> 4, l16 = lane & 15;
    const int pxt = lbid % PT, colIdx = lbid / PT;
    const int m0 = pxt * 32;
    const int b2 = m0 / HW, rem = m0 - b2*HW;
    const int y0 = rem / W, x0 = rem - (rem/W)*W;
    const int co0 = colIdx * 8;

    if (!first){
        const ushort* gsrc = hprev + (size_t)b2*HP*WP*CO;
        for (int c = tid; c < TOT; c += 256){
            int pix = c / CH8, ch = c - pix*CH8;
            int prow = pix / PPX, ppx = pix - prow*PPX;
            *(uint4*)&patch[pix*PCO + ch*8] =
                *(const uint4*)(gsrc + ((size_t)(y0+prow)*WP + (x0+ppx))*CO + ch*8);
        }
        __syncthreads();

        const int tn0 = colIdx*2;
        const ushort* bptr0 = Whpk + ((size_t)tn0*KCH*64 + lane)*8;
        const ushort* bptr1 = Whpk + ((size_t)(tn0+1)*KCH*64 + lane)*8;

        int labase[2];
        #pragma unroll
        for (int s = 0; s < 2; ++s){
            int pp = s*16 + l16;
            int rp = pp / W_T, xp = pp - rp*W_T;
            labase[s] = (rp*PPX + xp)*PCO + quad*8;
        }

        f32x4 acc[2][2] = {};
        const int nj = (KCH - wave + 3) >> 2;
        #pragma unroll
        for (int j = 0; j < NJ; ++j){
            if (j < nj){
                const int it = wave + 4*j;
                const int tap = it / CPT, ci0 = (it - tap*CPT)*32;
                const int kh = tap/3, kw = tap - (tap/3)*3;
                const int off = (kh*PPX + kw)*PCO + ci0;
                s16x8 b0 = *(const s16x8*)(bptr0 + (size_t)it*512);
                s16x8 b1 = *(const s16x8*)(bptr1 + (size_t)it*512);
                s16x8 a0 = *(const s16x8*)&patch[labase[0] + off];
                s16x8 a1 = *(const s16x8*)&patch[labase[1] + off];
                acc[0][0] = __builtin_amdgcn_mfma_f32_16x16x32_bf16(a0, b0, acc[0][0], 0,0,0);
                acc[0][1] = __builtin_amdgcn_mfma_f32_16x16x32_bf16(a0, b1, acc[0][1], 0,0,0);
                acc[1][0] = __builtin_amdgcn_mfma_f32_16x16x32_bf16(a1, b0, acc[1][0], 0,0,0);
                acc[1][1] = __builtin_amdgcn_mfma_f32_16x16x32_bf16(a1, b1, acc[1][1], 0,0,0);
            }
        }
        __syncthreads();   // patch dead; Zs overlays it
        #pragma unroll
        for (int s = 0; s < 2; ++s)
            #pragma unroll
            for (int nt = 0; nt < 2; ++nt)
                #pragma unroll
                for (int r = 0; r < 4; ++r)
                    Zs[(wave*32 + s*16 + quad*4 + r)*36 + nt*16 + l16] = acc[s][nt][r];
        __syncthreads();
    }

    // gates: 32 px x 8 co
    {
        const int px = tid >> 3, coin = tid & 7;
        const int m = m0 + px;
        const int rr = m - b2*HW;
        const int co = co0 + coin;
        const size_t zrow = (size_t)(b2*TSTEPS + t)*HW + rr;
        const float4 zx = *(const float4*)&Zx[zrow*N4 + colIdx*32 + coin*4];
        float zi = zx.x, zf = zx.y, zg = zx.z, zo = zx.w;
        if (!first){
            #pragma unroll
            for (int w = 0; w < 4; ++w){
                const float4 s = *(const float4*)&Zs[(w*32 + px)*36 + coin*4];
                zi += s.x; zf += s.y; zg += s.z; zo += s.w;
            }
        }
        const float iv = hsig(zi), fv = hsig(zf);
        const float gv = tanhf(zg), ov = hsig(zo);
        const float cold = first ? 0.f : cst[(size_t)m*CO + co];
        const float cn = fv*cold + iv*gv;
        cst[(size_t)m*CO + co] = cn;
        const float h = ov * tanhf(cn);
        const int y = rr / W, x = rr - (rr/W)*W;
        hnew[((size_t)b2*HP*WP + (y+1)*WP + (x+1))*CO + co] = f2bf(h);
        Hs[px*8 + coin] = (h - mmean[co])*rsqrtf(mvar[co]+1e-3f)*gamma[co] + beta[co];
    }
    __syncthreads();

    if (OUT_BF16){
        if (tid < 128){
            const int px = tid >> 2, q = tid & 3;
            const int ypos = q >> 1, xpos = q & 1;
            const int m = m0 + px;
            const int rr = m - b2*HW;
            const int y = rr / W, x = rr - (rr/W)*W;
            const float* hs = &Hs[px*8];
            uint4 v;
            v.x = pack2bf(hs[0], hs[1]); v.y = pack2bf(hs[2], hs[3]);
            v.z = pack2bf(hs[4], hs[5]); v.w = pack2bf(hs[6], hs[7]);
            ushort* o = (ushort*)outp;
            const size_t opix = ((size_t)(b2*TSTEPS + t)*(2*H+2) + 2*y+1+ypos)*(size_t)(2*W+2) + 2*x+1+xpos;
            *(uint4*)&o[opix*CO + co0] = v;
        }
    } else {
        const int px = tid >> 3, q = (tid >> 1) & 3, half = tid & 1;
        const int ypos = q >> 1, xpos = q & 1;
        const int m = m0 + px;
        const int rr = m - b2*HW;
        const int y = rr / W, x = rr - (rr/W)*W;
        float4 v = *(const float4*)&Hs[px*8 + half*4];
        float* o = (float*)outp;
        const size_t opix = ((size_t)(b2*TSTEPS + t)*(2*H) + 2*y+ypos)*(size_t)(2*W) + 2*x+xpos;
        *(float4*)&o[opix*CO + co0 + half*4] = v;
    }
}

// ---------------------------------------------------------------------------
// Fallback kernels (proven multi-launch path, round-2 structure).
// ---------------------------------------------------------------------------
__global__ __launch_bounds__(256) void prep_kernel_g(Params p){
    int i = blockIdx.x*256 + threadIdx.x;
    if (i < SZ_PREP) prep_elem(i, p);
}

__global__ __launch_bounds__(256) void convx1_all(Params p){
    __shared__ __align__(16) char smem[28800];
    conv_slice_role<192,128,16,16>(smem, blockIdx.x & 63, blockIdx.x >> 6,
                                   p.xpad, p.Wxp1, p.b1, p.Zx1);
}

__global__ __launch_bounds__(256) void mega_fb(Params p, int e1, int e2, int e3, int e4,
    int t1, int t2, int t3, int t4, int t5)
{
    __shared__ __align__(16) char smem[28800];
    const int bid = blockIdx.x;
    if (bid < e1){
        const ushort* hp = (t1 & 1) ? p.h1B : p.h1A; ushort* hn = (t1 & 1) ? p.h1A : p.h1B;
        step_role<128,16,16,1>(smem, bid, t1, t1==0, p.Zx1, p.Whp1, hp, hn,
                               p.c1, p.g1, p.be1, p.mm1, p.mv1, p.x2pad);
        return;
    }
    if (bid < e2){
        conv_slice_role<128,64,32,32>(smem, bid - e1, t2, p.x2pad, p.Wxp2, p.b2, p.Zx2);
        return;
    }
    if (bid < e3){
        const ushort* hp = (t3 & 1) ? p.h2B : p.h2A; ushort* hn = (t3 & 1) ? p.h2A : p.h2B;
        step_role<64,32,32,1>(smem, bid - e2, t3, t3==0, p.Zx2, p.Whp2, hp, hn,
                              p.c2, p.g2, p.be2, p.mm2, p.mv2, p.x3pad);
        return;
    }
    if (bid < e4){
        conv_slice_role<64,32,64,64>(smem, bid - e3, t4, p.x3pad, p.Wxp3, p.b3, p.Zx3);
        return;
    }
    {
        const ushort* hp = (t5 & 1) ? p.h3B : p.h3A; ushort* hn = (t5 & 1) ? p.h3A : p.h3B;
        step_role<32,64,64,0>(smem, bid - e4, t5, t5==0, p.Zx3, p.Whp3, hp, hn,
                              p.c3, p.g3, p.be3, p.mm3, p.mv3, p.out);
    }
}

// ---------------------------------------------------------------------------
// Persistent cooperative kernel. NBLK=768 (needs 3 blk/CU; capability 4-5).
// ---------------------------------------------------------------------------
__global__ __launch_bounds__(256, 4) void mega_persist(Params p)
{
    __shared__ __align__(16) char smem[28800];
    cg::grid_group grid = cg::this_grid();

    const int tid = threadIdx.x;
    const int bid = blockIdx.x;
    const int gtid = bid*256 + tid;
    constexpr int GSTRIDE = NBLK*256;

    // phase A: zero pads + h halo buffers (17,685,504 B = 1,105,344 uint4)
    {
        uint4 z = {0,0,0,0};
        uint4* zp = (uint4*)p.zbase;
        for (int i = gtid; i < 1105344; i += GSTRIDE) zp[i] = z;
    }
    __threadfence();
    grid.sync();

    // phase B: prep (bf16 pad + weight packing)
    for (int i = gtid; i < SZ_PREP; i += GSTRIDE) prep_elem(i, p);
    __threadfence();
    grid.sync();

    // phase C: pipeline. iter jj: {Cx1(jj), S1(jj-1), C2(jj-2), S2(jj-3), C3(jj-4), S3(jj-5)}
    for (int jj = 0; jj <= 12; ++jj){
        const int aC1 = (jj <= 7);
        const int aS1 = (jj >= 1 && jj <= 8);
        const int aC2 = (jj >= 2 && jj <= 9);
        const int aS2 = (jj >= 3 && jj <= 10);
        const int aC3 = (jj >= 4 && jj <= 11);
        const int aS3 = (jj >= 5);
        const int e0 = (aC1 ? 64 : 0);
        const int e1 = e0 + (aS1 ? 256 : 0);
        const int e2 = e1 + (aC2 ? 128 : 0);
        const int e3 = e2 + (aS2 ? 512 : 0);
        const int e4 = e3 + (aC3 ? 256 : 0);
        const int e5 = e4 + (aS3 ? 1024 : 0);

        for (int tt = bid; tt < e5; tt += NBLK){
            __syncthreads();   // guard LDS reuse between consecutive tiles
            if (tt < e0){
                conv_slice_role<192,128,16,16>(smem, tt, jj, p.xpad, p.Wxp1, p.b1, p.Zx1);
            } else if (tt < e1){
                const int t = jj-1;
                const ushort* hp = (t & 1) ? p.h1B : p.h1A;
                ushort*       hn = (t & 1) ? p.h1A : p.h1B;
                step_role<128,16,16,1>(smem, tt-e0, t, t==0, p.Zx1, p.Whp1, hp, hn,
                                       p.c1, p.g1, p.be1, p.mm1, p.mv1, p.x2pad);
            } else if (tt < e2){
                conv_slice_role<128,64,32,32>(smem, tt-e1, jj-2, p.x2pad, p.Wxp2, p.b2, p.Zx2);
            } else if (tt < e3){
                const int t = jj-3;
                const ushort* hp = (t & 1) ? p.h2B : p.h2A;
                ushort*       hn = (t & 1) ? p.h2A : p.h2B;
                step_role<64,32,32,1>(smem, tt-e2, t, t==0, p.Zx2, p.Whp2, hp, hn,
                                      p.c2, p.g2, p.be2, p.mm2, p.mv2, p.x3pad);
            } else if (tt < e4){
                conv_slice_role<64,32,64,64>(smem, tt-e3, jj-4, p.x3pad, p.Wxp3, p.b3, p.Zx3);
            } else {
                const int t = jj-5;
                const ushort* hp = (t & 1) ? p.h3B : p.h3A;
                ushort*       hn = (t & 1) ? p.h3A : p.h3B;
                step_role<32,64,64,0>(smem, tt-e4, t, t==0, p.Zx3, p.Whp3, hp, hn,
                                      p.c3, p.g3, p.be3, p.mm3, p.mv3, p.out);
            }
        }
        __threadfence();
        grid.sync();
    }
}

extern "C" void kernel_launch(void* const* d_in, const int* in_sizes, int n_in,
                              void* d_out, int out_size, void* d_ws, size_t ws_size,
                              hipStream_t stream) {
    Params p;
    p.x   = (const float*)d_in[0];
    p.Wx1 = (const float*)d_in[1];  p.Wh1 = (const float*)d_in[2];
    p.b1  = (const float*)d_in[3];  p.g1  = (const float*)d_in[4];
    p.be1 = (const float*)d_in[5];  p.mm1 = (const float*)d_in[6];
    p.mv1 = (const float*)d_in[7];
    p.Wx2 = (const float*)d_in[8];  p.Wh2 = (const float*)d_in[9];
    p.b2  = (const float*)d_in[10]; p.g2  = (const float*)d_in[11];
    p.be2 = (const float*)d_in[12]; p.mm2 = (const float*)d_in[13];
    p.mv2 = (const float*)d_in[14];
    p.Wx3 = (const float*)d_in[15]; p.Wh3 = (const float*)d_in[16];
    p.b3  = (const float*)d_in[17]; p.g3  = (const float*)d_in[18];
    p.be3 = (const float*)d_in[19]; p.mm3 = (const float*)d_in[20];
    p.mv3 = (const float*)d_in[21];

    char* ws = (char*)d_ws;
    size_t off = 0;
    auto alloc = [&](size_t bytes) { char* q = ws + off; off += (bytes + 255) & ~(size_t)255; return q; };

    p.Zx1 = (float*)alloc(2097152ull * 4);
    p.Zx2 = (float*)alloc(4194304ull * 4);
    p.Zx3 = (float*)alloc(8388608ull * 4);
    p.c1  = (float*)alloc(65536ull * 4);
    p.c2  = (float*)alloc(131072ull * 4);
    p.c3  = (float*)alloc(262144ull * 4);

    p.zbase = alloc(17685504ull);
    p.xpad  = (ushort*)p.zbase;
    p.x2pad = p.xpad  + 995328;
    p.x3pad = p.x2pad + 2367488;
    p.h1A   = p.x3pad + 4460544;
    p.h1B   = p.h1A + 82944;
    p.h2A   = p.h1B + 82944;
    p.h2B   = p.h2A + 147968;
    p.h3A   = p.h2B + 147968;
    p.h3B   = p.h3A + 278784;

    p.Wxp1 = (ushort*)alloc(884736ull * 2);
    p.Wxp2 = (ushort*)alloc(294912ull * 2);
    p.Wxp3 = (ushort*)alloc(73728ull * 2);
    p.Whp1 = (ushort*)alloc(589824ull * 2);
    p.Whp2 = (ushort*)alloc(147456ull * 2);
    p.Whp3 = (ushort*)alloc(36864ull * 2);

    p.out = (float*)d_out;

    void* args[] = { &p };
    hipError_t cerr = hipLaunchCooperativeKernel((void*)mega_persist, dim3(NBLK), dim3(256),
                                                 args, 0, stream);
    if (cerr != hipSuccess){
        (void)hipGetLastError();   // clear error state
        // fallback: proven multi-launch pipeline (round-2 structure)
        hipMemsetAsync(p.zbase, 0, 17685504ull, stream);
        prep_kernel_g<<<(SZ_PREP + 255) / 256, 256, 0, stream>>>(p);
        convx1_all<<<512, 256, 0, stream>>>(p);
        for (int j = 0; j < 12; ++j){
            const int a1 = (j < 8),             t1  = a1 ? j     : 0;
            const int a2 = (j >= 1 && j <= 8),  tc2 = a2 ? j - 1 : 0;
            const int a3 = (j >= 2 && j <= 9),  ts2 = a3 ? j - 2 : 0;
            const int a4 = (j >= 3 && j <= 10), tc3 = a4 ? j - 3 : 0;
            const int a5 = (j >= 4),            ts3 = a5 ? j - 4 : 0;

            const int e1 = a1 ? 256 : 0;
            const int e2 = e1 + (a2 ? 128 : 0);
            const int e3 = e2 + (a3 ? 512 : 0);
            const int e4 = e3 + (a4 ? 256 : 0);
            const int e5 = e4 + (a5 ? 1024 : 0);
            if (e5 == 0) continue;

            mega_fb<<<dim3(e5), 256, 0, stream>>>(p, e1, e2, e3, e4,
                                                  t1, tc2, ts2, tc3, ts3);
        }
    }
}

// Round 5
// 258.168 us; speedup vs baseline: 11.8812x; 11.8812x over previous
//
#include <hip/hip_runtime.h>
#include <math.h>

#define BATCH 2
#define TSTEPS 8

typedef __attribute__((ext_vector_type(8))) short s16x8;   // 8 bf16
typedef __attribute__((ext_vector_type(4))) float f32x4;   // MFMA accum

__device__ __forceinline__ float hsig(float v){ return fminf(fmaxf(0.2f*v+0.5f,0.f),1.f); }
__device__ __forceinline__ ushort f2bf(float f){
    uint u = __builtin_bit_cast(uint, f);
    u = (u + 0x7FFFu + ((u >> 16) & 1u)) >> 16;
    return (ushort)u;
}
__device__ __forceinline__ uint pack2bf(float lo, float hi){
    return (uint)f2bf(lo) | ((uint)f2bf(hi) << 16);
}

// pack W[k][g*Co+co] fp32 -> fragment-linear bf16
template<int KCH, int Co>
__device__ __forceinline__ void packw(const float* __restrict__ W, ushort* __restrict__ dst, int d){
    int j = d & 7, lane = (d >> 3) & 63;
    int q = lane >> 4, l = lane & 15;
    int rest = d >> 9;
    int c = rest % KCH, t_n = rest / KCH;
    int k = c*32 + q*8 + j;
    int np = t_n*16 + l;
    int g = np & 3, co = np >> 2;
    dst[d] = f2bf(W[(size_t)k*(4*Co) + g*Co + co]);
}

#define SZ_X    786432
#define SZ_WX1  884736
#define SZ_WH1  589824
#define SZ_WX2  294912
#define SZ_WH2  147456
#define SZ_WX3  73728
#define SZ_WH3  36864
#define SZ_PREP (SZ_X+SZ_WX1+SZ_WH1+SZ_WX2+SZ_WH2+SZ_WX3+SZ_WH3)

struct Params {
    const float *x, *Wx1, *Wh1, *b1, *g1, *be1, *mm1, *mv1;
    const float *Wx2, *Wh2, *b2, *g2, *be2, *mm2, *mv2;
    const float *Wx3, *Wh3, *b3, *g3, *be3, *mm3, *mv3;
    float *c1, *c2, *c3;
    char  *zbase;
    ushort *xpad, *x2pad, *x3pad, *h1A, *h1B, *h2A, *h2B, *h3A, *h3B;
    ushort *Wxp1, *Wxp2, *Wxp3, *Whp1, *Whp2, *Whp3;
    float *out;
};

__device__ __forceinline__ void prep_elem(int i, const Params& p){
    if (i < SZ_X){
        int c = i % 192; int r = i / 192;
        int xx = r % 16; r /= 16; int yy = r % 16; int bt = r / 16;
        p.xpad[((size_t)bt*18*18 + (yy+1)*18 + (xx+1))*192 + c] = f2bf(p.x[i]);
        return;
    } i -= SZ_X;
    if (i < SZ_WX1){ packw<54,128>(p.Wx1, p.Wxp1, i); return; } i -= SZ_WX1;
    if (i < SZ_WH1){ packw<36,128>(p.Wh1, p.Whp1, i); return; } i -= SZ_WH1;
    if (i < SZ_WX2){ packw<36, 64>(p.Wx2, p.Wxp2, i); return; } i -= SZ_WX2;
    if (i < SZ_WH2){ packw<18, 64>(p.Wh2, p.Whp2, i); return; } i -= SZ_WH2;
    if (i < SZ_WX3){ packw<18, 32>(p.Wx3, p.Wxp3, i); return; } i -= SZ_WX3;
    if (i < SZ_WH3){ packw< 9, 32>(p.Wh3, p.Whp3, i); }
}

__global__ __launch_bounds__(256) void prep_kernel_g(Params p){
    int i = blockIdx.x*256 + threadIdx.x;
    if (i < SZ_PREP) prep_elem(i, p);
}

// ---------------------------------------------------------------------------
// Fused ConvLSTM step role: x-conv (K=9*CI) + h-conv (K=9*CO) split-K over
// 4 waves into the same accumulators, one LDS reduce, fused bias+gates+BN+
// 2x2 upsample. wg = 32 px x 32 interleaved cols. Zs/h-patch overlay x-patch.
// lbid in [0, PT*NC) with PT = BATCH*H*W/32, NC = 4*CO/32.
// ---------------------------------------------------------------------------
template<int CI, int CO, int H, int W, int OUT_BF16>
__device__ __forceinline__ void fused_role(char* smem, int lbid, int t, int first,
    const ushort* __restrict__ Apad, const ushort* __restrict__ Wxpk,
    const ushort* __restrict__ hprev, const ushort* __restrict__ Whpk,
    const float* __restrict__ bias,
    ushort* __restrict__ hnew, float* __restrict__ cst,
    const float* __restrict__ gamma, const float* __restrict__ beta,
    const float* __restrict__ mmean, const float* __restrict__ mvar,
    void* __restrict__ outp)
{
    constexpr int W_T = (W < 32) ? W : 32;
    constexpr int PR = (32/W_T) + 2, PPX = W_T + 2;
    constexpr int PCI = CI + 8, PCO = CO + 8;
    constexpr int KX = 9*CI/32, CPTX = CI/32;
    constexpr int KH = 9*CO/32, CPTH = CO/32;
    constexpr int NJX = (KX + 3)/4, NJH = (KH + 3)/4;
    constexpr int HW = H*W, HP = H+2, WP = W+2;
    constexpr int CH8X = CI/8, CH8H = CO/8;
    constexpr int TOTX = PR*PPX*CH8X, TOTH = PR*PPX*CH8H;
    constexpr int PT = (BATCH*HW)/32;

    ushort* patch = (ushort*)smem;
    float* Zs = (float*)smem;                   // overlay, [4][32][36] = 18432 B
    float* Hs = (float*)(smem + 18432);         // [32][8]

    const int tid = threadIdx.x, lane = tid & 63, wave = tid >> 6;
    const int quad = lane >> 4, l16 = lane & 15;
    const int pxt = lbid % PT, colIdx = lbid / PT;
    const int m0 = pxt * 32;
    const int b2 = m0 / HW, rem = m0 - b2*HW;
    const int y0 = rem / W, x0 = rem - (rem/W)*W;
    const int co0 = colIdx * 8;
    const int tn0 = colIdx * 2;
    const int bt = b2*TSTEPS + t;

    f32x4 acc[2][2] = {};

    // ---- phase 1: x-conv ----
    {
        const ushort* gsrc = Apad + (size_t)bt*HP*WP*CI;
        for (int c = tid; c < TOTX; c += 256){
            int pix = c / CH8X, ch = c - pix*CH8X;
            int prow = pix / PPX, ppx = pix - prow*PPX;
            *(uint4*)&patch[pix*PCI + ch*8] =
                *(const uint4*)(gsrc + ((size_t)(y0+prow)*WP + (x0+ppx))*CI + ch*8);
        }
        __syncthreads();

        const ushort* bp0 = Wxpk + ((size_t)tn0*KX*64 + lane)*8;
        const ushort* bp1 = Wxpk + ((size_t)(tn0+1)*KX*64 + lane)*8;
        int labase[2];
        #pragma unroll
        for (int s = 0; s < 2; ++s){
            int pp = s*16 + l16;
            int rp = pp / W_T, xp = pp - rp*W_T;
            labase[s] = (rp*PPX + xp)*PCI + quad*8;
        }
        const int nj = (KX - wave + 3) >> 2;
        #pragma unroll
        for (int j = 0; j < NJX; ++j){
            if (j < nj){
                const int it = wave + 4*j;
                const int tap = it / CPTX, ci0 = (it - tap*CPTX)*32;
                const int kh = tap/3, kw = tap - (tap/3)*3;
                const int off = (kh*PPX + kw)*PCI + ci0;
                s16x8 b0 = *(const s16x8*)(bp0 + (size_t)it*512);
                s16x8 b1 = *(const s16x8*)(bp1 + (size_t)it*512);
                s16x8 a0 = *(const s16x8*)&patch[labase[0] + off];
                s16x8 a1 = *(const s16x8*)&patch[labase[1] + off];
                acc[0][0] = __builtin_amdgcn_mfma_f32_16x16x32_bf16(a0, b0, acc[0][0], 0,0,0);
                acc[0][1] = __builtin_amdgcn_mfma_f32_16x16x32_bf16(a0, b1, acc[0][1], 0,0,0);
                acc[1][0] = __builtin_amdgcn_mfma_f32_16x16x32_bf16(a1, b0, acc[1][0], 0,0,0);
                acc[1][1] = __builtin_amdgcn_mfma_f32_16x16x32_bf16(a1, b1, acc[1][1], 0,0,0);
            }
        }
        __syncthreads();   // x-patch dead
    }

    // ---- phase 2: h-conv (skipped at t==0; h==0) ----
    if (!first){
        const ushort* gsrc = hprev + (size_t)b2*HP*WP*CO;
        for (int c = tid; c < TOTH; c += 256){
            int pix = c / CH8H, ch = c - pix*CH8H;
            int prow = pix / PPX, ppx = pix - prow*PPX;
            *(uint4*)&patch[pix*PCO + ch*8] =
                *(const uint4*)(gsrc + ((size_t)(y0+prow)*WP + (x0+ppx))*CO + ch*8);
        }
        __syncthreads();

        const ushort* bp0 = Whpk + ((size_t)tn0*KH*64 + lane)*8;
        const ushort* bp1 = Whpk + ((size_t)(tn0+1)*KH*64 + lane)*8;
        int labase[2];
        #pragma unroll
        for (int s = 0; s < 2; ++s){
            int pp = s*16 + l16;
            int rp = pp / W_T, xp = pp - rp*W_T;
            labase[s] = (rp*PPX + xp)*PCO + quad*8;
        }
        const int nj = (KH - wave + 3) >> 2;
        #pragma unroll
        for (int j = 0; j < NJH; ++j){
            if (j < nj){
                const int it = wave + 4*j;
                const int tap = it / CPTH, ci0 = (it - tap*CPTH)*32;
                const int kh = tap/3, kw = tap - (tap/3)*3;
                const int off = (kh*PPX + kw)*PCO + ci0;
                s16x8 b0 = *(const s16x8*)(bp0 + (size_t)it*512);
                s16x8 b1 = *(const s16x8*)(bp1 + (size_t)it*512);
                s16x8 a0 = *(const s16x8*)&patch[labase[0] + off];
                s16x8 a1 = *(const s16x8*)&patch[labase[1] + off];
                acc[0][0] = __builtin_amdgcn_mfma_f32_16x16x32_bf16(a0, b0, acc[0][0], 0,0,0);
                acc[0][1] = __builtin_amdgcn_mfma_f32_16x16x32_bf16(a0, b1, acc[0][1], 0,0,0);
                acc[1][0] = __builtin_amdgcn_mfma_f32_16x16x32_bf16(a1, b0, acc[1][0], 0,0,0);
                acc[1][1] = __builtin_amdgcn_mfma_f32_16x16x32_bf16(a1, b1, acc[1][1], 0,0,0);
            }
        }
        __syncthreads();   // h-patch dead
    }

    // ---- phase 3: split-K reduce via LDS ----
    #pragma unroll
    for (int s = 0; s < 2; ++s)
        #pragma unroll
        for (int nt = 0; nt < 2; ++nt)
            #pragma unroll
            for (int r = 0; r < 4; ++r)
                Zs[(wave*32 + s*16 + quad*4 + r)*36 + nt*16 + l16] = acc[s][nt][r];
    __syncthreads();

    // ---- phase 4: gates + BN (32 px x 8 co) ----
    {
        const int px = tid >> 3, coin = tid & 7;
        const int m = m0 + px;
        const int rr = m - b2*HW;
        const int co = co0 + coin;
        float zi = 0.f, zf = 0.f, zg = 0.f, zo = 0.f;
        #pragma unroll
        for (int w = 0; w < 4; ++w){
            const float4 s = *(const float4*)&Zs[(w*32 + px)*36 + coin*4];
            zi += s.x; zf += s.y; zg += s.z; zo += s.w;
        }
        zi += bias[0*CO + co]; zf += bias[1*CO + co];
        zg += bias[2*CO + co]; zo += bias[3*CO + co];
        const float iv = hsig(zi), fv = hsig(zf);
        const float gv = tanhf(zg), ov = hsig(zo);
        const float cold = first ? 0.f : cst[(size_t)m*CO + co];
        const float cn = fv*cold + iv*gv;
        cst[(size_t)m*CO + co] = cn;
        const float h = ov * tanhf(cn);
        const int y = rr / W, x = rr - (rr/W)*W;
        hnew[((size_t)b2*HP*WP + (y+1)*WP + (x+1))*CO + co] = f2bf(h);
        Hs[px*8 + coin] = (h - mmean[co])*rsqrtf(mvar[co]+1e-3f)*gamma[co] + beta[co];
    }
    __syncthreads();

    // ---- phase 5: 2x2 upsample write ----
    if (OUT_BF16){
        if (tid < 128){
            const int px = tid >> 2, q = tid & 3;
            const int ypos = q >> 1, xpos = q & 1;
            const int m = m0 + px;
            const int rr = m - b2*HW;
            const int y = rr / W, x = rr - (rr/W)*W;
            const float* hs = &Hs[px*8];
            uint4 v;
            v.x = pack2bf(hs[0], hs[1]); v.y = pack2bf(hs[2], hs[3]);
            v.z = pack2bf(hs[4], hs[5]); v.w = pack2bf(hs[6], hs[7]);
            ushort* o = (ushort*)outp;
            const size_t opix = ((size_t)bt*(2*H+2) + 2*y+1+ypos)*(size_t)(2*W+2) + 2*x+1+xpos;
            *(uint4*)&o[opix*CO + co0] = v;
        }
    } else {
        const int px = tid >> 3, q = (tid >> 1) & 3, half = tid & 1;
        const int ypos = q >> 1, xpos = q & 1;
        const int m = m0 + px;
        const int rr = m - b2*HW;
        const int y = rr / W, x = rr - (rr/W)*W;
        float4 v = *(const float4*)&Hs[px*8 + half*4];
        float* o = (float*)outp;
        const size_t opix = ((size_t)bt*(2*H) + 2*y+ypos)*(size_t)(2*W) + 2*x+xpos;
        *(float4*)&o[opix*CO + co0 + half*4] = v;
    }
}

// ---------------------------------------------------------------------------
// Mega pipeline kernel: up to 3 fused step roles per launch.
// LDS max = S1f x-patch 4*18*200*2 = 28800 B -> 5 blocks/CU.
// Role block counts: S1f=256, S2f=512, S3f=1024.
// ---------------------------------------------------------------------------
__global__ __launch_bounds__(256) void mega(Params p, int e1, int e2,
                                            int t1, int t2, int t3)
{
    __shared__ __align__(16) char smem[28800];
    const int bid = blockIdx.x;
    if (bid < e1){
        const ushort* hp = (t1 & 1) ? p.h1B : p.h1A;
        ushort*       hn = (t1 & 1) ? p.h1A : p.h1B;
        fused_role<192,128,16,16,1>(smem, bid, t1, t1==0,
            p.xpad, p.Wxp1, hp, p.Whp1, p.b1, hn, p.c1,
            p.g1, p.be1, p.mm1, p.mv1, p.x2pad);
    } else if (bid < e2){
        const ushort* hp = (t2 & 1) ? p.h2B : p.h2A;
        ushort*       hn = (t2 & 1) ? p.h2A : p.h2B;
        fused_role<128,64,32,32,1>(smem, bid - e1, t2, t2==0,
            p.x2pad, p.Wxp2, hp, p.Whp2, p.b2, hn, p.c2,
            p.g2, p.be2, p.mm2, p.mv2, p.x3pad);
    } else {
        const ushort* hp = (t3 & 1) ? p.h3B : p.h3A;
        ushort*       hn = (t3 & 1) ? p.h3A : p.h3B;
        fused_role<64,32,64,64,0>(smem, bid - e2, t3, t3==0,
            p.x3pad, p.Wxp3, hp, p.Whp3, p.b3, hn, p.c3,
            p.g3, p.be3, p.mm3, p.mv3, p.out);
    }
}

extern "C" void kernel_launch(void* const* d_in, const int* in_sizes, int n_in,
                              void* d_out, int out_size, void* d_ws, size_t ws_size,
                              hipStream_t stream) {
    Params p;
    p.x   = (const float*)d_in[0];
    p.Wx1 = (const float*)d_in[1];  p.Wh1 = (const float*)d_in[2];
    p.b1  = (const float*)d_in[3];  p.g1  = (const float*)d_in[4];
    p.be1 = (const float*)d_in[5];  p.mm1 = (const float*)d_in[6];
    p.mv1 = (const float*)d_in[7];
    p.Wx2 = (const float*)d_in[8];  p.Wh2 = (const float*)d_in[9];
    p.b2  = (const float*)d_in[10]; p.g2  = (const float*)d_in[11];
    p.be2 = (const float*)d_in[12]; p.mm2 = (const float*)d_in[13];
    p.mv2 = (const float*)d_in[14];
    p.Wx3 = (const float*)d_in[15]; p.Wh3 = (const float*)d_in[16];
    p.b3  = (const float*)d_in[17]; p.g3  = (const float*)d_in[18];
    p.be3 = (const float*)d_in[19]; p.mm3 = (const float*)d_in[20];
    p.mv3 = (const float*)d_in[21];

    char* ws = (char*)d_ws;
    size_t off = 0;
    auto alloc = [&](size_t bytes) { char* q = ws + off; off += (bytes + 255) & ~(size_t)255; return q; };

    p.c1  = (float*)alloc(65536ull * 4);
    p.c2  = (float*)alloc(131072ull * 4);
    p.c3  = (float*)alloc(262144ull * 4);

    // contiguous zero region (one memset): pads + h halo buffers
    p.zbase = alloc(17685504ull);
    p.xpad  = (ushort*)p.zbase;                //  995,328 u (16x18x18x192)
    p.x2pad = p.xpad  + 995328;                // 2,367,488 u (16x34x34x128)
    p.x3pad = p.x2pad + 2367488;               // 4,460,544 u (16x66x66x64)
    p.h1A   = p.x3pad + 4460544;               //    82,944 u (2x18x18x128)
    p.h1B   = p.h1A + 82944;
    p.h2A   = p.h1B + 82944;                   //   147,968 u (2x34x34x64)
    p.h2B   = p.h2A + 147968;
    p.h3A   = p.h2B + 147968;                  //   278,784 u (2x66x66x32)
    p.h3B   = p.h3A + 278784;

    p.Wxp1 = (ushort*)alloc(884736ull * 2);
    p.Wxp2 = (ushort*)alloc(294912ull * 2);
    p.Wxp3 = (ushort*)alloc(73728ull * 2);
    p.Whp1 = (ushort*)alloc(589824ull * 2);
    p.Whp2 = (ushort*)alloc(147456ull * 2);
    p.Whp3 = (ushort*)alloc(36864ull * 2);

    p.out = (float*)d_out;

    hipMemsetAsync(p.zbase, 0, 17685504ull, stream);

    prep_kernel_g<<<(SZ_PREP + 255) / 256, 256, 0, stream>>>(p);

    // pipeline: launch j runs { S1f(j), S2f(j-1), S3f(j-2) }
    for (int j = 0; j <= 9; ++j){
        const int aS1 = (j <= 7);
        const int aS2 = (j >= 1 && j <= 8);
        const int aS3 = (j >= 2);
        const int e1 = aS1 ? 256 : 0;
        const int e2 = e1 + (aS2 ? 512 : 0);
        const int e3 = e2 + (aS3 ? 1024 : 0);
        const int t1 = aS1 ? j     : 0;
        const int t2 = aS2 ? j - 1 : 0;
        const int t3 = aS3 ? j - 2 : 0;
        mega<<<dim3(e3), 256, 0, stream>>>(p, e1, e2, t1, t2, t3);
    }
}

// Round 6
// 257.151 us; speedup vs baseline: 11.9282x; 1.0040x over previous
//
#include <hip/hip_runtime.h>
#include <math.h>

#define BATCH 2
#define TSTEPS 8

typedef __attribute__((ext_vector_type(8))) short s16x8;   // 8 bf16
typedef __attribute__((ext_vector_type(4))) float f32x4;   // MFMA accum

__device__ __forceinline__ float hsig(float v){ return fminf(fmaxf(0.2f*v+0.5f,0.f),1.f); }
__device__ __forceinline__ ushort f2bf(float f){
    uint u = __builtin_bit_cast(uint, f);
    u = (u + 0x7FFFu + ((u >> 16) & 1u)) >> 16;
    return (ushort)u;
}
__device__ __forceinline__ uint pack2bf(float lo, float hi){
    return (uint)f2bf(lo) | ((uint)f2bf(hi) << 16);
}

// pack W[k][g*Co+co] fp32 -> fragment-linear bf16, K padded to KCHP (zeros)
template<int KCH, int KCHP, int Co>
__device__ __forceinline__ void packw(const float* __restrict__ W, ushort* __restrict__ dst, int d){
    int j = d & 7, lane = (d >> 3) & 63;
    int q = lane >> 4, l = lane & 15;
    int rest = d >> 9;
    int c = rest % KCHP, t_n = rest / KCHP;
    if (c >= KCH){ dst[d] = 0; return; }
    int k = c*32 + q*8 + j;
    int np = t_n*16 + l;
    int g = np & 3, co = np >> 2;
    dst[d] = f2bf(W[(size_t)k*(4*Co) + g*Co + co]);
}

#define SZ_X    786432
#define SZ_WX1  917504   // 32 tiles * 56 * 512
#define SZ_WH1  589824   // 32 * 36 * 512
#define SZ_WX2  294912   // 16 * 36 * 512
#define SZ_WH2  163840   // 16 * 20 * 512
#define SZ_WX3   81920   //  8 * 20 * 512
#define SZ_WH3   49152   //  8 * 12 * 512
#define SZ_PREP (SZ_X+SZ_WX1+SZ_WH1+SZ_WX2+SZ_WH2+SZ_WX3+SZ_WH3)

struct Params {
    const float *x, *Wx1, *Wh1, *b1, *g1, *be1, *mm1, *mv1;
    const float *Wx2, *Wh2, *b2, *g2, *be2, *mm2, *mv2;
    const float *Wx3, *Wh3, *b3, *g3, *be3, *mm3, *mv3;
    float *c1, *c2, *c3;
    char  *zbase;
    ushort *xpad, *x2pad, *x3pad, *h1A, *h1B, *h2A, *h2B, *h3A, *h3B;
    ushort *Wxp1, *Wxp2, *Wxp3, *Whp1, *Whp2, *Whp3;
    float *out;
};

__device__ __forceinline__ void prep_elem(int i, const Params& p){
    if (i < SZ_X){
        int c = i % 192; int r = i / 192;
        int xx = r % 16; r /= 16; int yy = r % 16; int bt = r / 16;
        p.xpad[((size_t)bt*18*18 + (yy+1)*18 + (xx+1))*192 + c] = f2bf(p.x[i]);
        return;
    } i -= SZ_X;
    if (i < SZ_WX1){ packw<54,56,128>(p.Wx1, p.Wxp1, i); return; } i -= SZ_WX1;
    if (i < SZ_WH1){ packw<36,36,128>(p.Wh1, p.Whp1, i); return; } i -= SZ_WH1;
    if (i < SZ_WX2){ packw<36,36, 64>(p.Wx2, p.Wxp2, i); return; } i -= SZ_WX2;
    if (i < SZ_WH2){ packw<18,20, 64>(p.Wh2, p.Whp2, i); return; } i -= SZ_WH2;
    if (i < SZ_WX3){ packw<18,20, 32>(p.Wx3, p.Wxp3, i); return; } i -= SZ_WX3;
    if (i < SZ_WH3){ packw< 9,12, 32>(p.Wh3, p.Whp3, i); }
}

__global__ __launch_bounds__(256) void prep_kernel_g(Params p){
    int i = blockIdx.x*256 + threadIdx.x;
    if (i < SZ_PREP) prep_elem(i, p);
}

// ---------------------------------------------------------------------------
// Fused ConvLSTM step role. NCPB col-groups (32 cols each) per block:
// stage patch once, x-conv + h-conv split-K (K padded to x4, branch-free)
// into acc[NCPB][2][2], LDS reduce, fused bias+gates+BN+2x2 upsample.
// ---------------------------------------------------------------------------
template<int CI, int CO, int H, int W, int OUT_BF16, int NCPB>
__device__ __forceinline__ void fused_role(char* smem, int lbid, int t, int first,
    const ushort* __restrict__ Apad, const ushort* __restrict__ Wxpk,
    const ushort* __restrict__ hprev, const ushort* __restrict__ Whpk,
    const float* __restrict__ bias,
    ushort* __restrict__ hnew, float* __restrict__ cst,
    const float* __restrict__ gamma, const float* __restrict__ beta,
    const float* __restrict__ mmean, const float* __restrict__ mvar,
    void* __restrict__ outp)
{
    constexpr int W_T = (W < 32) ? W : 32;
    constexpr int PR = (32/W_T) + 2, PPX = W_T + 2;
    constexpr int PCI = CI + 8, PCO = CO + 8;
    constexpr int KX = 9*CI/32, CPTX = CI/32;
    constexpr int KH = 9*CO/32, CPTH = CO/32;
    constexpr int KXP = (KX + 3) & ~3, KHP = (KH + 3) & ~3;
    constexpr int NJX = KXP/4, NJH = KHP/4;
    constexpr int HW = H*W, HP = H+2, WP = W+2;
    constexpr int CH8X = CI/8, CH8H = CO/8;
    constexpr int TOTX = PR*PPX*CH8X, TOTH = PR*PPX*CH8H;
    constexpr int PT = (BATCH*HW)/32;

    ushort* patch = (ushort*)smem;
    float* Zs = (float*)smem;                        // overlay, NCPB*[4][32][36]
    float* Hs = (float*)(smem + NCPB*18432);         // NCPB*[32][8]

    const int tid = threadIdx.x, lane = tid & 63, wave = tid >> 6;
    const int quad = lane >> 4, l16 = lane & 15;
    const int pxt = lbid % PT, colB = lbid / PT;
    const int m0 = pxt * 32;
    const int b2 = m0 / HW, rem = m0 - b2*HW;
    const int y0 = rem / W, x0 = rem - (rem/W)*W;
    const int bt = b2*TSTEPS + t;

    f32x4 acc[NCPB][2][2] = {};

    int labaseX[2], labaseH[2];
    #pragma unroll
    for (int s = 0; s < 2; ++s){
        int pp = s*16 + l16;
        int rp = pp / W_T, xp = pp - rp*W_T;
        labaseX[s] = (rp*PPX + xp)*PCI + quad*8;
        labaseH[s] = (rp*PPX + xp)*PCO + quad*8;
    }

    // ---- phase 1: x-conv ----
    {
        const ushort* gsrc = Apad + (size_t)bt*HP*WP*CI;
        for (int c = tid; c < TOTX; c += 256){
            int pix = c / CH8X, ch = c - pix*CH8X;
            int prow = pix / PPX, ppx = pix - prow*PPX;
            *(uint4*)&patch[pix*PCI + ch*8] =
                *(const uint4*)(gsrc + ((size_t)(y0+prow)*WP + (x0+ppx))*CI + ch*8);
        }
        __syncthreads();

        const ushort* bp[NCPB][2];
        #pragma unroll
        for (int cc = 0; cc < NCPB; ++cc){
            const int tn = (colB*NCPB + cc)*2;
            bp[cc][0] = Wxpk + ((size_t)tn*KXP*64 + lane)*8;
            bp[cc][1] = Wxpk + ((size_t)(tn+1)*KXP*64 + lane)*8;
        }
        #pragma unroll
        for (int j = 0; j < NJX; ++j){
            const int it = wave + 4*j;
            const int itA = (it < KX) ? it : 0;      // pad taps: B=0, clamp A addr
            const int tap = itA / CPTX, ci0 = (itA - tap*CPTX)*32;
            const int kh = tap/3, kw = tap - (tap/3)*3;
            const int off = (kh*PPX + kw)*PCI + ci0;
            s16x8 a0 = *(const s16x8*)&patch[labaseX[0] + off];
            s16x8 a1 = *(const s16x8*)&patch[labaseX[1] + off];
            #pragma unroll
            for (int cc = 0; cc < NCPB; ++cc){
                s16x8 b0 = *(const s16x8*)(bp[cc][0] + (size_t)it*512);
                s16x8 b1 = *(const s16x8*)(bp[cc][1] + (size_t)it*512);
                acc[cc][0][0] = __builtin_amdgcn_mfma_f32_16x16x32_bf16(a0, b0, acc[cc][0][0], 0,0,0);
                acc[cc][0][1] = __builtin_amdgcn_mfma_f32_16x16x32_bf16(a0, b1, acc[cc][0][1], 0,0,0);
                acc[cc][1][0] = __builtin_amdgcn_mfma_f32_16x16x32_bf16(a1, b0, acc[cc][1][0], 0,0,0);
                acc[cc][1][1] = __builtin_amdgcn_mfma_f32_16x16x32_bf16(a1, b1, acc[cc][1][1], 0,0,0);
            }
        }
        __syncthreads();   // x-patch dead
    }

    // ---- phase 2: h-conv (skipped at t==0; h==0) ----
    if (!first){
        const ushort* gsrc = hprev + (size_t)b2*HP*WP*CO;
        for (int c = tid; c < TOTH; c += 256){
            int pix = c / CH8H, ch = c - pix*CH8H;
            int prow = pix / PPX, ppx = pix - prow*PPX;
            *(uint4*)&patch[pix*PCO + ch*8] =
                *(const uint4*)(gsrc + ((size_t)(y0+prow)*WP + (x0+ppx))*CO + ch*8);
        }
        __syncthreads();

        const ushort* bp[NCPB][2];
        #pragma unroll
        for (int cc = 0; cc < NCPB; ++cc){
            const int tn = (colB*NCPB + cc)*2;
            bp[cc][0] = Whpk + ((size_t)tn*KHP*64 + lane)*8;
            bp[cc][1] = Whpk + ((size_t)(tn+1)*KHP*64 + lane)*8;
        }
        #pragma unroll
        for (int j = 0; j < NJH; ++j){
            const int it = wave + 4*j;
            const int itA = (it < KH) ? it : 0;
            const int tap = itA / CPTH, ci0 = (itA - tap*CPTH)*32;
            const int kh = tap/3, kw = tap - (tap/3)*3;
            const int off = (kh*PPX + kw)*PCO + ci0;
            s16x8 a0 = *(const s16x8*)&patch[labaseH[0] + off];
            s16x8 a1 = *(const s16x8*)&patch[labaseH[1] + off];
            #pragma unroll
            for (int cc = 0; cc < NCPB; ++cc){
                s16x8 b0 = *(const s16x8*)(bp[cc][0] + (size_t)it*512);
                s16x8 b1 = *(const s16x8*)(bp[cc][1] + (size_t)it*512);
                acc[cc][0][0] = __builtin_amdgcn_mfma_f32_16x16x32_bf16(a0, b0, acc[cc][0][0], 0,0,0);
                acc[cc][0][1] = __builtin_amdgcn_mfma_f32_16x16x32_bf16(a0, b1, acc[cc][0][1], 0,0,0);
                acc[cc][1][0] = __builtin_amdgcn_mfma_f32_16x16x32_bf16(a1, b0, acc[cc][1][0], 0,0,0);
                acc[cc][1][1] = __builtin_amdgcn_mfma_f32_16x16x32_bf16(a1, b1, acc[cc][1][1], 0,0,0);
            }
        }
        __syncthreads();   // h-patch dead
    }

    // ---- phase 3: split-K reduce via LDS ----
    #pragma unroll
    for (int cc = 0; cc < NCPB; ++cc)
        #pragma unroll
        for (int s = 0; s < 2; ++s)
            #pragma unroll
            for (int nt = 0; nt < 2; ++nt)
                #pragma unroll
                for (int r = 0; r < 4; ++r)
                    Zs[cc*4608 + (wave*32 + s*16 + quad*4 + r)*36 + nt*16 + l16] = acc[cc][s][nt][r];
    __syncthreads();

    // ---- phase 4: gates + BN (32 px x 8 co per cc) ----
    #pragma unroll
    for (int cc = 0; cc < NCPB; ++cc){
        const int px = tid >> 3, coin = tid & 7;
        const int m = m0 + px;
        const int rr = m - b2*HW;
        const int co = (colB*NCPB + cc)*8 + coin;
        float zi = 0.f, zf = 0.f, zg = 0.f, zo = 0.f;
        #pragma unroll
        for (int w = 0; w < 4; ++w){
            const float4 s = *(const float4*)&Zs[cc*4608 + (w*32 + px)*36 + coin*4];
            zi += s.x; zf += s.y; zg += s.z; zo += s.w;
        }
        zi += bias[0*CO + co]; zf += bias[1*CO + co];
        zg += bias[2*CO + co]; zo += bias[3*CO + co];
        const float iv = hsig(zi), fv = hsig(zf);
        const float gv = tanhf(zg), ov = hsig(zo);
        const float cold = first ? 0.f : cst[(size_t)m*CO + co];
        const float cn = fv*cold + iv*gv;
        cst[(size_t)m*CO + co] = cn;
        const float h = ov * tanhf(cn);
        const int y = rr / W, x = rr - (rr/W)*W;
        hnew[((size_t)b2*HP*WP + (y+1)*WP + (x+1))*CO + co] = f2bf(h);
        Hs[cc*256 + px*8 + coin] = (h - mmean[co])*rsqrtf(mvar[co]+1e-3f)*gamma[co] + beta[co];
    }
    __syncthreads();

    // ---- phase 5: 2x2 upsample write ----
    #pragma unroll
    for (int cc = 0; cc < NCPB; ++cc){
        const int co0 = (colB*NCPB + cc)*8;
        if (OUT_BF16){
            if (tid < 128){
                const int px = tid >> 2, q = tid & 3;
                const int ypos = q >> 1, xpos = q & 1;
                const int m = m0 + px;
                const int rr = m - b2*HW;
                const int y = rr / W, x = rr - (rr/W)*W;
                const float* hs = &Hs[cc*256 + px*8];
                uint4 v;
                v.x = pack2bf(hs[0], hs[1]); v.y = pack2bf(hs[2], hs[3]);
                v.z = pack2bf(hs[4], hs[5]); v.w = pack2bf(hs[6], hs[7]);
                ushort* o = (ushort*)outp;
                const size_t opix = ((size_t)bt*(2*H+2) + 2*y+1+ypos)*(size_t)(2*W+2) + 2*x+1+xpos;
                *(uint4*)&o[opix*CO + co0] = v;
            }
        } else {
            const int px = tid >> 3, q = (tid >> 1) & 3, half = tid & 1;
            const int ypos = q >> 1, xpos = q & 1;
            const int m = m0 + px;
            const int rr = m - b2*HW;
            const int y = rr / W, x = rr - (rr/W)*W;
            float4 v = *(const float4*)&Hs[cc*256 + px*8 + half*4];
            float* o = (float*)outp;
            const size_t opix = ((size_t)bt*(2*H) + 2*y+ypos)*(size_t)(2*W) + 2*x+xpos;
            *(float4*)&o[opix*CO + co0 + half*4] = v;
        }
    }
}

// ---------------------------------------------------------------------------
// Mega: {S1f (NCPB=1, 256 blk), S2f (NCPB=2, 256 blk), S3f (NCPB=2, 512 blk)}.
// LDS = 38912 B -> 4 blocks/CU; launch_bounds(256,4) -> VGPR<=128 -> 4/CU.
// Steady grid = 1024 = exactly one resident round.
// ---------------------------------------------------------------------------
__global__ __launch_bounds__(256, 4) void mega(Params p, int e1, int e2,
                                               int t1, int t2, int t3)
{
    __shared__ __align__(16) char smem[38912];
    const int bid = blockIdx.x;
    if (bid < e1){
        const ushort* hp = (t1 & 1) ? p.h1B : p.h1A;
        ushort*       hn = (t1 & 1) ? p.h1A : p.h1B;
        fused_role<192,128,16,16,1,1>(smem, bid, t1, t1==0,
            p.xpad, p.Wxp1, hp, p.Whp1, p.b1, hn, p.c1,
            p.g1, p.be1, p.mm1, p.mv1, p.x2pad);
    } else if (bid < e2){
        const ushort* hp = (t2 & 1) ? p.h2B : p.h2A;
        ushort*       hn = (t2 & 1) ? p.h2A : p.h2B;
        fused_role<128,64,32,32,1,2>(smem, bid - e1, t2, t2==0,
            p.x2pad, p.Wxp2, hp, p.Whp2, p.b2, hn, p.c2,
            p.g2, p.be2, p.mm2, p.mv2, p.x3pad);
    } else {
        const ushort* hp = (t3 & 1) ? p.h3B : p.h3A;
        ushort*       hn = (t3 & 1) ? p.h3A : p.h3B;
        fused_role<64,32,64,64,0,2>(smem, bid - e2, t3, t3==0,
            p.x3pad, p.Wxp3, hp, p.Whp3, p.b3, hn, p.c3,
            p.g3, p.be3, p.mm3, p.mv3, p.out);
    }
}

extern "C" void kernel_launch(void* const* d_in, const int* in_sizes, int n_in,
                              void* d_out, int out_size, void* d_ws, size_t ws_size,
                              hipStream_t stream) {
    Params p;
    p.x   = (const float*)d_in[0];
    p.Wx1 = (const float*)d_in[1];  p.Wh1 = (const float*)d_in[2];
    p.b1  = (const float*)d_in[3];  p.g1  = (const float*)d_in[4];
    p.be1 = (const float*)d_in[5];  p.mm1 = (const float*)d_in[6];
    p.mv1 = (const float*)d_in[7];
    p.Wx2 = (const float*)d_in[8];  p.Wh2 = (const float*)d_in[9];
    p.b2  = (const float*)d_in[10]; p.g2  = (const float*)d_in[11];
    p.be2 = (const float*)d_in[12]; p.mm2 = (const float*)d_in[13];
    p.mv2 = (const float*)d_in[14];
    p.Wx3 = (const float*)d_in[15]; p.Wh3 = (const float*)d_in[16];
    p.b3  = (const float*)d_in[17]; p.g3  = (const float*)d_in[18];
    p.be3 = (const float*)d_in[19]; p.mm3 = (const float*)d_in[20];
    p.mv3 = (const float*)d_in[21];

    char* ws = (char*)d_ws;
    size_t off = 0;
    auto alloc = [&](size_t bytes) { char* q = ws + off; off += (bytes + 255) & ~(size_t)255; return q; };

    p.c1  = (float*)alloc(65536ull * 4);
    p.c2  = (float*)alloc(131072ull * 4);
    p.c3  = (float*)alloc(262144ull * 4);

    // contiguous zero region (one memset): pads + h halo buffers
    p.zbase = alloc(17685504ull);
    p.xpad  = (ushort*)p.zbase;                //  995,328 u (16x18x18x192)
    p.x2pad = p.xpad  + 995328;                // 2,367,488 u (16x34x34x128)
    p.x3pad = p.x2pad + 2367488;               // 4,460,544 u (16x66x66x64)
    p.h1A   = p.x3pad + 4460544;               //    82,944 u (2x18x18x128)
    p.h1B   = p.h1A + 82944;
    p.h2A   = p.h1B + 82944;                   //   147,968 u (2x34x34x64)
    p.h2B   = p.h2A + 147968;
    p.h3A   = p.h2B + 147968;                  //   278,784 u (2x66x66x32)
    p.h3B   = p.h3A + 278784;

    p.Wxp1 = (ushort*)alloc((size_t)SZ_WX1 * 2);
    p.Wxp2 = (ushort*)alloc((size_t)SZ_WX2 * 2);
    p.Wxp3 = (ushort*)alloc((size_t)SZ_WX3 * 2);
    p.Whp1 = (ushort*)alloc((size_t)SZ_WH1 * 2);
    p.Whp2 = (ushort*)alloc((size_t)SZ_WH2 * 2);
    p.Whp3 = (ushort*)alloc((size_t)SZ_WH3 * 2);

    p.out = (float*)d_out;

    hipMemsetAsync(p.zbase, 0, 17685504ull, stream);

    prep_kernel_g<<<(SZ_PREP + 255) / 256, 256, 0, stream>>>(p);

    // pipeline: launch j runs { S1f(j), S2f(j-1), S3f(j-2) }
    for (int j = 0; j <= 9; ++j){
        const int aS1 = (j <= 7);
        const int aS2 = (j >= 1 && j <= 8);
        const int aS3 = (j >= 2);
        const int e1 = aS1 ? 256 : 0;
        const int e2 = e1 + (aS2 ? 256 : 0);
        const int e3 = e2 + (aS3 ? 512 : 0);
        const int t1 = aS1 ? j     : 0;
        const int t2 = aS2 ? j - 1 : 0;
        const int t3 = aS3 ? j - 2 : 0;
        mega<<<dim3(e3), 256, 0, stream>>>(p, e1, e2, t1, t2, t3);
    }
}